// Round 1
// baseline (146.848 us; speedup 1.0000x reference)
//
#include <hip/hip_runtime.h>
#include <hip/hip_bf16.h>

// Problem constants (fixed by reference): B=1,R=2,D=256,NH=8,NP=8,ZA=4,H=W=128,Q=16384,HD=32
#define QN 16384
#define DK 256

typedef float f4_t __attribute__((ext_vector_type(4)));
typedef short s16x8 __attribute__((ext_vector_type(8)));

__device__ inline unsigned short bfr(float f){
  unsigned u = __builtin_bit_cast(unsigned, f);
  unsigned r = (u + 0x7FFFu + ((u >> 16) & 1u)) >> 16;   // round-to-nearest-even
  return (unsigned short)r;
}
__device__ inline float bf2f(short s){
  unsigned u = ((unsigned)(unsigned short)s) << 16;
  return __builtin_bit_cast(float, u);
}

// ---------------- weight pre-convert (f32 -> bf16, row-major K=256) -------------
// rows 0..255 = W_val, 256..383 = W_off, 384..447 = W_attn, 448..703 = W_out
__global__ __launch_bounds__(256) void k_convw(const float* __restrict__ Wv,
    const float* __restrict__ Woff, const float* __restrict__ Wattn,
    const float* __restrict__ Wout, short* __restrict__ Wbf){
  const int row = blockIdx.x;
  const int c = threadIdx.x;
  const float* src;
  if (row < 256)       src = Wv    + (size_t)row * DK;
  else if (row < 384)  src = Woff  + (size_t)(row - 256) * DK;
  else if (row < 448)  src = Wattn + (size_t)(row - 384) * DK;
  else                 src = Wout  + (size_t)(row - 448) * DK;
  Wbf[(size_t)row * DK + c] = (short)bfr(src[c]);
}

// ---------------- shared MFMA GEMM core: C[m][n] = A[m][:] . B[n][:] ------------
// A: row-major [M][256] (f32 or bf16), B: row-major bf16 [N][256]
// Wave computes 16 rows x NT*16 cols. Fragment maps (m89-verified):
//   a[j] = A[lane&15][(lane>>4)*8 + j],  b[j] = B[n=nt*16+(lane&15)][(lane>>4)*8+j]
//   d[r] = D[(lane>>4)*4 + r][lane&15]
template<int NT, bool ABF16>
__device__ inline void gemm_core(const void* __restrict__ Aptr,
                                 const short* __restrict__ B,
                                 int mrow, f4_t* acc){
  const int lane = threadIdx.x & 63;
  const int r16 = lane & 15;
  const int kh  = lane >> 4;
  #pragma unroll
  for (int kk = 0; kk < 8; ++kk){
    const int ko = kh * 8 + kk * 32;
    s16x8 a;
    if constexpr (ABF16){
      a = *(const s16x8*)((const short*)Aptr + (size_t)(mrow + r16) * DK + ko);
    } else {
      const float* ap = (const float*)Aptr + (size_t)(mrow + r16) * DK + ko;
      const f4_t a0 = *(const f4_t*)ap;
      const f4_t a1 = *(const f4_t*)(ap + 4);
      #pragma unroll
      for (int i = 0; i < 4; ++i){ a[i] = (short)bfr(a0[i]); a[i+4] = (short)bfr(a1[i]); }
    }
    const short* bp = B + r16 * DK + ko;
    #pragma unroll
    for (int nt = 0; nt < NT; ++nt){
      const s16x8 b = *(const s16x8*)(bp + nt * 16 * DK);
      acc[nt] = __builtin_amdgcn_mfma_f32_16x16x32_bf16(a, b, acc[nt], 0, 0, 0);
    }
  }
}

// ---------------- K1: value projection -> v_bf[r][h][pix][hd] bf16 --------------
__global__ __launch_bounds__(256) void k_gemm_val(const float* __restrict__ value,
    const short* __restrict__ Wv, const float* __restrict__ bval,
    short* __restrict__ vbf){
  const int wave = threadIdx.x >> 6;
  const int mrow = blockIdx.x * 64 + wave * 16;
  f4_t acc[16];
  #pragma unroll
  for (int i = 0; i < 16; ++i) acc[i] = (f4_t){0.f, 0.f, 0.f, 0.f};
  gemm_core<16, false>(value, Wv, mrow, acc);
  const int lane = threadIdx.x & 63;
  const int r16 = lane & 15, kh = lane >> 4;
  #pragma unroll
  for (int nt = 0; nt < 16; ++nt){
    const int n = nt * 16 + r16;
    const int h = n >> 5, hd = n & 31;
    const float bv = bval[n];
    #pragma unroll
    for (int rix = 0; rix < 4; ++rix){
      const int row = mrow + kh * 4 + rix;     // global m = r*16384 + pix
      const int r = row >> 14;
      const int pix = row & (QN - 1);
      vbf[(size_t)((r * 8 + h) * QN + pix) * 32 + hd] = (short)bfr(acc[nt][rix] + bv);
    }
  }
}

// ---------------- K2: offsets (raw) + attention logits ---------------------------
__global__ __launch_bounds__(256) void k_gemm_oa(const float* __restrict__ query,
    const short* __restrict__ Woa, const float* __restrict__ boff,
    const float* __restrict__ battn, float* __restrict__ offw,
    float* __restrict__ logit){
  const int wave = threadIdx.x >> 6;
  const int mrow = blockIdx.x * 64 + wave * 16;
  f4_t acc[12];
  #pragma unroll
  for (int i = 0; i < 12; ++i) acc[i] = (f4_t){0.f, 0.f, 0.f, 0.f};
  gemm_core<12, false>(query, Woa, mrow, acc);
  const int lane = threadIdx.x & 63;
  const int r16 = lane & 15, kh = lane >> 4;
  #pragma unroll
  for (int nt = 0; nt < 12; ++nt){
    const int n = nt * 16 + r16;
    #pragma unroll
    for (int rix = 0; rix < 4; ++rix){
      const int row = mrow + kh * 4 + rix;
      const float v = acc[nt][rix];
      if (n < 128) offw[(size_t)row * 128 + n] = v + boff[n];
      else         logit[(size_t)row * 64 + (n - 128)] = v + battn[n - 128];
    }
  }
}

// ---------------- K3: bilinear deformable sampling -------------------------------
// block = 256 thr = 64 query-groups x 4 lanes; one head per block (h = bid&7 -> XCD)
// output O2[q][h*32+hd] f32 = 0.5 * sum_r sum_p aw[p] * bilinear(v[r][h], loc)
__global__ __launch_bounds__(256) void k_sampler(const float* __restrict__ rp,
    const float* __restrict__ offw, const float* __restrict__ logit,
    const short* __restrict__ vbf, float* __restrict__ O2){
  const int tid = threadIdx.x;
  const int j = tid & 3;                 // hd slice: [8j, 8j+8)
  const int grp = tid >> 2;
  const int h = blockIdx.x & 7;
  const int q = (blockIdx.x >> 3) * 64 + grp;

  // softmax over 8 points (NL*NP = 8), fold 0.5 mean-over-R
  const float* lp = logit + (size_t)q * 64 + h * 8;
  float aw[8];
  float mx = lp[0];
  #pragma unroll
  for (int p = 1; p < 8; ++p) mx = fmaxf(mx, lp[p]);
  float s = 0.f;
  #pragma unroll
  for (int p = 0; p < 8; ++p){ float e = __expf(lp[p] - mx); aw[p] = e; s += e; }
  const float sc = 0.5f / s;
  #pragma unroll
  for (int p = 0; p < 8; ++p) aw[p] *= sc;

  const float* offp = offw + (size_t)q * 128 + h * 16;
  float acc[8] = {0.f,0.f,0.f,0.f,0.f,0.f,0.f,0.f};

  for (int r = 0; r < 2; ++r){
    const float* rpb = rp + (size_t)(r * QN + q) * 8;     // [za=4][2]
    const short* vb = vbf + (size_t)((r * 8 + h) * QN) * 32 + j * 8;
    #pragma unroll
    for (int p = 0; p < 8; ++p){
      // x = (rp.x + off.x/128)*128 - 0.5 = rp.x*128 + off.x - 0.5 ; za = p&3
      const float x = fmaf(rpb[(p & 3) * 2 + 0], 128.f, offp[p * 2 + 0]) - 0.5f;
      const float y = fmaf(rpb[(p & 3) * 2 + 1], 128.f, offp[p * 2 + 1]) - 0.5f;
      const float xf = floorf(x), yf = floorf(y);
      const float wx = x - xf, wy = y - yf;
      const int ix = (int)xf, iy = (int)yf;
      const float vx0 = (ix >= 0 && ix < 128) ? 1.f : 0.f;
      const float vx1 = (ix + 1 >= 0 && ix + 1 < 128) ? 1.f : 0.f;
      const float vy0 = (iy >= 0 && iy < 128) ? 1.f : 0.f;
      const float vy1 = (iy + 1 >= 0 && iy + 1 < 128) ? 1.f : 0.f;
      const int ix0 = min(max(ix, 0), 127), ix1 = min(max(ix + 1, 0), 127);
      const int iy0 = min(max(iy, 0), 127), iy1 = min(max(iy + 1, 0), 127);
      const float a = aw[p];
      const float w00 = a * (1.f - wx) * (1.f - wy) * vx0 * vy0;
      const float w01 = a * wx * (1.f - wy) * vx1 * vy0;
      const float w10 = a * (1.f - wx) * wy * vx0 * vy1;
      const float w11 = a * wx * wy * vx1 * vy1;
      const s16x8 c00 = *(const s16x8*)(vb + (size_t)(iy0 * 128 + ix0) * 32);
      const s16x8 c01 = *(const s16x8*)(vb + (size_t)(iy0 * 128 + ix1) * 32);
      const s16x8 c10 = *(const s16x8*)(vb + (size_t)(iy1 * 128 + ix0) * 32);
      const s16x8 c11 = *(const s16x8*)(vb + (size_t)(iy1 * 128 + ix1) * 32);
      #pragma unroll
      for (int e = 0; e < 8; ++e){
        acc[e] = fmaf(w00, bf2f(c00[e]), acc[e]);
        acc[e] = fmaf(w01, bf2f(c01[e]), acc[e]);
        acc[e] = fmaf(w10, bf2f(c10[e]), acc[e]);
        acc[e] = fmaf(w11, bf2f(c11[e]), acc[e]);
      }
    }
  }
  float* op = O2 + (size_t)q * DK + h * 32 + j * 8;
  *(f4_t*)op       = (f4_t){acc[0], acc[1], acc[2], acc[3]};
  *(f4_t*)(op + 4) = (f4_t){acc[4], acc[5], acc[6], acc[7]};
}

// ---------------- K4: output projection + bias + residual ------------------------
__global__ __launch_bounds__(256) void k_gemm_out(const float* __restrict__ O2,
    const short* __restrict__ Wo, const float* __restrict__ bout,
    const float* __restrict__ query, float* __restrict__ out){
  const int wave = threadIdx.x >> 6;
  const int mrow = blockIdx.x * 64 + wave * 16;
  f4_t acc[16];
  #pragma unroll
  for (int i = 0; i < 16; ++i) acc[i] = (f4_t){0.f, 0.f, 0.f, 0.f};
  gemm_core<16, false>(O2, Wo, mrow, acc);
  const int lane = threadIdx.x & 63;
  const int r16 = lane & 15, kh = lane >> 4;
  #pragma unroll
  for (int nt = 0; nt < 16; ++nt){
    const int n = nt * 16 + r16;
    const float bo = bout[n];
    #pragma unroll
    for (int rix = 0; rix < 4; ++rix){
      const int row = mrow + kh * 4 + rix;
      out[(size_t)row * DK + n] = acc[nt][rix] + bo + query[(size_t)row * DK + n];
    }
  }
}

extern "C" void kernel_launch(void* const* d_in, const int* in_sizes, int n_in,
                              void* d_out, int out_size, void* d_ws, size_t ws_size,
                              hipStream_t stream) {
  const float* query = (const float*)d_in[0];
  const float* value = (const float*)d_in[1];
  const float* refpt = (const float*)d_in[2];
  // d_in[3] spatial_shapes: fixed [[128,128]], hardcoded
  const float* W_off  = (const float*)d_in[4];
  const float* b_off  = (const float*)d_in[5];
  const float* W_attn = (const float*)d_in[6];
  const float* b_attn = (const float*)d_in[7];
  const float* W_val  = (const float*)d_in[8];
  const float* b_val  = (const float*)d_in[9];
  const float* W_out  = (const float*)d_in[10];
  const float* b_out  = (const float*)d_in[11];
  float* out = (float*)d_out;

  char* ws = (char*)d_ws;
  short* Wbf  = (short*)(ws);                    // 704*256 bf16          (360448 B)
  short* vbf  = (short*)(ws + 360448);           // 2*8*16384*32 bf16     (16777216 B)
  float* offw = (float*)(ws + 17137664);         // 16384*128 f32         (8388608 B)
  float* logit= (float*)(ws + 25526272);         // 16384*64 f32          (4194304 B)
  float* O2   = (float*)(ws + 29720576);         // 16384*256 f32         (16777216 B)

  k_convw   <<<dim3(704),  dim3(256), 0, stream>>>(W_val, W_off, W_attn, W_out, Wbf);
  k_gemm_val<<<dim3(512),  dim3(256), 0, stream>>>(value, Wbf, b_val, vbf);
  k_gemm_oa <<<dim3(256),  dim3(256), 0, stream>>>(query, Wbf + 256 * DK, b_off, b_attn, offw, logit);
  k_sampler <<<dim3(2048), dim3(256), 0, stream>>>(refpt, offw, logit, vbf, O2);
  k_gemm_out<<<dim3(256),  dim3(256), 0, stream>>>(O2, Wbf + 448 * DK, b_out, query, out);
}

// Round 2
// 137.044 us; speedup vs baseline: 1.0715x; 1.0715x over previous
//
#include <hip/hip_runtime.h>
#include <hip/hip_bf16.h>

// Problem constants (fixed by reference): B=1,R=2,D=256,NH=8,NP=8,ZA=4,H=W=128,Q=16384,HD=32
#define QN 16384
#define DK 256

typedef float f4_t __attribute__((ext_vector_type(4)));
typedef short s16x8 __attribute__((ext_vector_type(8)));

__device__ inline short f2bf(float f){
  __hip_bfloat16 h = __float2bfloat16(f);          // compiler emits v_cvt_pk_bf16_f32
  return __builtin_bit_cast(short, h);
}
__device__ inline float bf2f(short s){
  unsigned u = ((unsigned)(unsigned short)s) << 16;
  return __builtin_bit_cast(float, u);
}

// ---------------- weight pre-convert (f32 -> bf16, row-major K=256) -------------
// rows 0..255 = W_val, 256..383 = W_off, 384..447 = W_attn, 448..703 = W_out
__global__ __launch_bounds__(256) void k_convw(const float* __restrict__ Wv,
    const float* __restrict__ Woff, const float* __restrict__ Wattn,
    const float* __restrict__ Wout, short* __restrict__ Wbf){
  const int row = blockIdx.x;
  const int c = threadIdx.x;
  const float* src;
  if (row < 256)       src = Wv    + (size_t)row * DK;
  else if (row < 384)  src = Woff  + (size_t)(row - 256) * DK;
  else if (row < 448)  src = Wattn + (size_t)(row - 384) * DK;
  else                 src = Wout  + (size_t)(row - 448) * DK;
  Wbf[(size_t)row * DK + c] = f2bf(src[c]);
}

// ---------------- shared MFMA GEMM core: C[m][n] = A[m][:] . B[n][:] ------------
// A: row-major f32 [M][256], B: row-major bf16 [N][256] (pass B pre-offset by colbase).
// Wave computes 16 rows x NT*16 cols. Fragment maps (m89-verified):
//   a[j] = A[lane&15][(lane>>4)*8 + j],  b[j] = B[nt*16+(lane&15)][(lane>>4)*8+j]
//   d[r] = D[(lane>>4)*4 + r][lane&15]
template<int NT>
__device__ inline void gemm_core(const float* __restrict__ A,
                                 const short* __restrict__ B,
                                 int mrow, f4_t* acc){
  const int lane = threadIdx.x & 63;
  const int r16 = lane & 15;
  const int kh  = lane >> 4;
  #pragma unroll
  for (int kk = 0; kk < 8; ++kk){
    const int ko = kh * 8 + kk * 32;
    const float* ap = A + (size_t)(mrow + r16) * DK + ko;
    const f4_t a0 = *(const f4_t*)ap;
    const f4_t a1 = *(const f4_t*)(ap + 4);
    s16x8 a;
    #pragma unroll
    for (int i = 0; i < 4; ++i){ a[i] = f2bf(a0[i]); a[i+4] = f2bf(a1[i]); }
    const short* bp = B + r16 * DK + ko;
    #pragma unroll
    for (int nt = 0; nt < NT; ++nt){
      const s16x8 b = *(const s16x8*)(bp + nt * 16 * DK);
      acc[nt] = __builtin_amdgcn_mfma_f32_16x16x32_bf16(a, b, acc[nt], 0, 0, 0);
    }
  }
}

// ---------------- K1: value projection -> v_bf[r][h][pix][hd] bf16 --------------
// block = 4 waves on ONE 16-row m-tile, each wave 64 cols (NT=4). Grid = M/16.
__global__ __launch_bounds__(256) void k_gemm_val(const float* __restrict__ value,
    const short* __restrict__ Wv, const float* __restrict__ bval,
    short* __restrict__ vbf){
  const int wave = threadIdx.x >> 6;
  const int mrow = blockIdx.x * 16;
  const int colbase = wave * 64;
  f4_t acc[4];
  #pragma unroll
  for (int i = 0; i < 4; ++i) acc[i] = (f4_t){0.f, 0.f, 0.f, 0.f};
  gemm_core<4>(value, Wv + (size_t)colbase * DK, mrow, acc);
  const int lane = threadIdx.x & 63;
  const int r16 = lane & 15, kh = lane >> 4;
  #pragma unroll
  for (int nt = 0; nt < 4; ++nt){
    const int n = colbase + nt * 16 + r16;
    const int h = n >> 5, hd = n & 31;
    const float bv = bval[n];
    #pragma unroll
    for (int rix = 0; rix < 4; ++rix){
      const int row = mrow + kh * 4 + rix;     // global m = r*16384 + pix
      const int r = row >> 14;
      const int pix = row & (QN - 1);
      vbf[(size_t)((r * 8 + h) * QN + pix) * 32 + hd] = f2bf(acc[nt][rix] + bv);
    }
  }
}

// ---------------- K2: offsets (raw) + attention logits ---------------------------
// block = 4 waves on ONE 16-row m-tile, each wave 48 cols (NT=3). Grid = 16384/16.
__global__ __launch_bounds__(256) void k_gemm_oa(const float* __restrict__ query,
    const short* __restrict__ Woa, const float* __restrict__ boff,
    const float* __restrict__ battn, float* __restrict__ offw,
    float* __restrict__ logit){
  const int wave = threadIdx.x >> 6;
  const int mrow = blockIdx.x * 16;
  const int colbase = wave * 48;
  f4_t acc[3];
  #pragma unroll
  for (int i = 0; i < 3; ++i) acc[i] = (f4_t){0.f, 0.f, 0.f, 0.f};
  gemm_core<3>(query, Woa + (size_t)colbase * DK, mrow, acc);
  const int lane = threadIdx.x & 63;
  const int r16 = lane & 15, kh = lane >> 4;
  #pragma unroll
  for (int nt = 0; nt < 3; ++nt){
    const int n = colbase + nt * 16 + r16;
    #pragma unroll
    for (int rix = 0; rix < 4; ++rix){
      const int row = mrow + kh * 4 + rix;
      const float v = acc[nt][rix];
      if (n < 128) offw[(size_t)row * 128 + n] = v + boff[n];
      else         logit[(size_t)row * 64 + (n - 128)] = v + battn[n - 128];
    }
  }
}

// ---------------- K3: bilinear deformable sampling -------------------------------
// block = 256 thr = 64 query-groups x 4 lanes; one head per block (h = bid&7 -> XCD)
// output O2[q][h*32+hd] f32 = 0.5 * sum_r sum_p aw[p] * bilinear(v[r][h], loc)
__global__ __launch_bounds__(256) void k_sampler(const float* __restrict__ rp,
    const float* __restrict__ offw, const float* __restrict__ logit,
    const short* __restrict__ vbf, float* __restrict__ O2){
  const int tid = threadIdx.x;
  const int j = tid & 3;                 // hd slice: [8j, 8j+8)
  const int grp = tid >> 2;
  const int h = blockIdx.x & 7;
  const int q = (blockIdx.x >> 3) * 64 + grp;

  // softmax over 8 points (NL*NP = 8), fold 0.5 mean-over-R
  const float* lp = logit + (size_t)q * 64 + h * 8;
  float aw[8];
  float mx = lp[0];
  #pragma unroll
  for (int p = 1; p < 8; ++p) mx = fmaxf(mx, lp[p]);
  float s = 0.f;
  #pragma unroll
  for (int p = 0; p < 8; ++p){ float e = __expf(lp[p] - mx); aw[p] = e; s += e; }
  const float sc = 0.5f / s;
  #pragma unroll
  for (int p = 0; p < 8; ++p) aw[p] *= sc;

  const float* offp = offw + (size_t)q * 128 + h * 16;
  float acc[8] = {0.f,0.f,0.f,0.f,0.f,0.f,0.f,0.f};

  for (int r = 0; r < 2; ++r){
    const float* rpb = rp + (size_t)(r * QN + q) * 8;     // [za=4][2]
    const short* vb = vbf + (size_t)((r * 8 + h) * QN) * 32 + j * 8;
    #pragma unroll
    for (int p = 0; p < 8; ++p){
      // x = (rp.x + off.x/128)*128 - 0.5 = rp.x*128 + off.x - 0.5 ; za = p&3
      const float x = fmaf(rpb[(p & 3) * 2 + 0], 128.f, offp[p * 2 + 0]) - 0.5f;
      const float y = fmaf(rpb[(p & 3) * 2 + 1], 128.f, offp[p * 2 + 1]) - 0.5f;
      const float xf = floorf(x), yf = floorf(y);
      const float wx = x - xf, wy = y - yf;
      const int ix = (int)xf, iy = (int)yf;
      const float vx0 = (ix >= 0 && ix < 128) ? 1.f : 0.f;
      const float vx1 = (ix + 1 >= 0 && ix + 1 < 128) ? 1.f : 0.f;
      const float vy0 = (iy >= 0 && iy < 128) ? 1.f : 0.f;
      const float vy1 = (iy + 1 >= 0 && iy + 1 < 128) ? 1.f : 0.f;
      const int ix0 = min(max(ix, 0), 127), ix1 = min(max(ix + 1, 0), 127);
      const int iy0 = min(max(iy, 0), 127), iy1 = min(max(iy + 1, 0), 127);
      const float a = aw[p];
      const float w00 = a * (1.f - wx) * (1.f - wy) * vx0 * vy0;
      const float w01 = a * wx * (1.f - wy) * vx1 * vy0;
      const float w10 = a * (1.f - wx) * wy * vx0 * vy1;
      const float w11 = a * wx * wy * vx1 * vy1;
      const s16x8 c00 = *(const s16x8*)(vb + (size_t)(iy0 * 128 + ix0) * 32);
      const s16x8 c01 = *(const s16x8*)(vb + (size_t)(iy0 * 128 + ix1) * 32);
      const s16x8 c10 = *(const s16x8*)(vb + (size_t)(iy1 * 128 + ix0) * 32);
      const s16x8 c11 = *(const s16x8*)(vb + (size_t)(iy1 * 128 + ix1) * 32);
      #pragma unroll
      for (int e = 0; e < 8; ++e){
        acc[e] = fmaf(w00, bf2f(c00[e]), acc[e]);
        acc[e] = fmaf(w01, bf2f(c01[e]), acc[e]);
        acc[e] = fmaf(w10, bf2f(c10[e]), acc[e]);
        acc[e] = fmaf(w11, bf2f(c11[e]), acc[e]);
      }
    }
  }
  float* op = O2 + (size_t)q * DK + h * 32 + j * 8;
  *(f4_t*)op       = (f4_t){acc[0], acc[1], acc[2], acc[3]};
  *(f4_t*)(op + 4) = (f4_t){acc[4], acc[5], acc[6], acc[7]};
}

// ---------------- K4: output projection + bias + residual ------------------------
// block = 4 waves on ONE 16-row m-tile, each wave 64 cols (NT=4). Grid = 16384/16.
__global__ __launch_bounds__(256) void k_gemm_out(const float* __restrict__ O2,
    const short* __restrict__ Wo, const float* __restrict__ bout,
    const float* __restrict__ query, float* __restrict__ out){
  const int wave = threadIdx.x >> 6;
  const int mrow = blockIdx.x * 16;
  const int colbase = wave * 64;
  f4_t acc[4];
  #pragma unroll
  for (int i = 0; i < 4; ++i) acc[i] = (f4_t){0.f, 0.f, 0.f, 0.f};
  gemm_core<4>(O2, Wo + (size_t)colbase * DK, mrow, acc);
  const int lane = threadIdx.x & 63;
  const int r16 = lane & 15, kh = lane >> 4;
  #pragma unroll
  for (int nt = 0; nt < 4; ++nt){
    const int n = colbase + nt * 16 + r16;
    const float bo = bout[n];
    #pragma unroll
    for (int rix = 0; rix < 4; ++rix){
      const int row = mrow + kh * 4 + rix;
      out[(size_t)row * DK + n] = acc[nt][rix] + bo + query[(size_t)row * DK + n];
    }
  }
}

extern "C" void kernel_launch(void* const* d_in, const int* in_sizes, int n_in,
                              void* d_out, int out_size, void* d_ws, size_t ws_size,
                              hipStream_t stream) {
  const float* query = (const float*)d_in[0];
  const float* value = (const float*)d_in[1];
  const float* refpt = (const float*)d_in[2];
  // d_in[3] spatial_shapes: fixed [[128,128]], hardcoded
  const float* W_off  = (const float*)d_in[4];
  const float* b_off  = (const float*)d_in[5];
  const float* W_attn = (const float*)d_in[6];
  const float* b_attn = (const float*)d_in[7];
  const float* W_val  = (const float*)d_in[8];
  const float* b_val  = (const float*)d_in[9];
  const float* W_out  = (const float*)d_in[10];
  const float* b_out  = (const float*)d_in[11];
  float* out = (float*)d_out;

  char* ws = (char*)d_ws;
  short* Wbf  = (short*)(ws);                    // 704*256 bf16          (360448 B)
  short* vbf  = (short*)(ws + 360448);           // 2*8*16384*32 bf16     (16777216 B)
  float* offw = (float*)(ws + 17137664);         // 16384*128 f32         (8388608 B)
  float* logit= (float*)(ws + 25526272);         // 16384*64 f32          (4194304 B)
  float* O2   = (float*)(ws + 29720576);         // 16384*256 f32         (16777216 B)

  k_convw   <<<dim3(704),  dim3(256), 0, stream>>>(W_val, W_off, W_attn, W_out, Wbf);
  k_gemm_val<<<dim3(2048), dim3(256), 0, stream>>>(value, Wbf, b_val, vbf);
  k_gemm_oa <<<dim3(1024), dim3(256), 0, stream>>>(query, Wbf + 256 * DK, b_off, b_attn, offw, logit);
  k_sampler <<<dim3(2048), dim3(256), 0, stream>>>(refpt, offw, logit, vbf, O2);
  k_gemm_out<<<dim3(1024), dim3(256), 0, stream>>>(O2, Wbf + 448 * DK, b_out, query, out);
}

// Round 3
// 82.244 us; speedup vs baseline: 1.7855x; 1.6663x over previous
//
#include <hip/hip_runtime.h>
#include <hip/hip_bf16.h>

// Problem constants: B=1,R=2,D=256,NH=8,NP=8,ZA=4,H=W=128,Q=16384,HD=32
#define QN 16384
#define DK 256

typedef float f4_t __attribute__((ext_vector_type(4)));
typedef short s16x8 __attribute__((ext_vector_type(8)));
typedef short s16x4 __attribute__((ext_vector_type(4)));

__device__ inline short f2bf(float f){
  __hip_bfloat16 h = __float2bfloat16(f);
  return __builtin_bit_cast(short, h);
}
__device__ inline float bf2f(short s){
  unsigned u = ((unsigned)(unsigned short)s) << 16;
  return __builtin_bit_cast(float, u);
}

// ---------------- weight pre-convert (f32 -> bf16, row-major K=256) -------------
// rows 0..255 = W_val, 256..383 = W_off, 384..447 = W_attn, 448..703 = W_out
__global__ __launch_bounds__(256) void k_convw(const float* __restrict__ Wv,
    const float* __restrict__ Woff, const float* __restrict__ Wattn,
    const float* __restrict__ Wout, short* __restrict__ Wbf){
  const int row = blockIdx.x;
  const int c = threadIdx.x;
  const float* src;
  if (row < 256)       src = Wv    + (size_t)row * DK;
  else if (row < 384)  src = Woff  + (size_t)(row - 256) * DK;
  else if (row < 448)  src = Wattn + (size_t)(row - 384) * DK;
  else                 src = Wout  + (size_t)(row - 448) * DK;
  Wbf[(size_t)row * DK + c] = f2bf(src[c]);
}

// =============== K1: value projection, LDS-staged MFMA GEMM =====================
// BM=64 rows/block, 4 waves (wave w = rows [16w,16w+16)), col-groups of 64 (x4).
// LDS: As[64][256]bf16 (32KB) + Bs[64][256]bf16 (32KB), both XOR-swizzled
// (byte ^= (row&7)<<4) so the stride-512B fragment reads are <=2-way conflicts.
__global__ __launch_bounds__(256, 2) void k_gemm_val(const float* __restrict__ A,
    const short* __restrict__ Bw, const float* __restrict__ bval,
    short* __restrict__ vbf){
  __shared__ short As[64 * 256];
  __shared__ short Bs[64 * 256];
  const int tid = threadIdx.x;
  const int lane = tid & 63, wv = tid >> 6;
  const int r16 = lane & 15, kh = lane >> 4;
  const int swsel = (r16 & 7) << 4;
  const int mbase = blockIdx.x * 64;

  // stage A: 64 rows x 256 f32 -> bf16, coalesced dwordx4 loads, ds_write_b64
  #pragma unroll
  for (int i = 0; i < 16; ++i){
    const int lin = i * 256 + tid;              // 16B-src chunk id (4 floats)
    const int r = lin >> 6, ck = lin & 63;
    const f4_t v = *(const f4_t*)(A + (size_t)(mbase + r) * DK + ck * 4);
    s16x4 o = { f2bf(v[0]), f2bf(v[1]), f2bf(v[2]), f2bf(v[3]) };
    *(s16x4*)((char*)As + r * 512 + ((ck * 8) ^ ((r & 7) << 4))) = o;
  }
  // preload B col-group 0 into regs (T14: issue-early / write-late)
  s16x8 breg[8];
  #pragma unroll
  for (int i = 0; i < 8; ++i){
    const int lin = i * 256 + tid;              // 16B chunk id in 32KB B tile
    const int n = lin >> 5, ck = lin & 31;
    breg[i] = *(const s16x8*)(Bw + (size_t)n * DK + ck * 8);
  }
  __syncthreads();

  for (int cg = 0; cg < 4; ++cg){
    #pragma unroll
    for (int i = 0; i < 8; ++i){
      const int lin = i * 256 + tid;
      const int n = lin >> 5, ck = lin & 31;
      *(s16x8*)((char*)Bs + n * 512 + ((ck * 16) ^ ((n & 7) << 4))) = breg[i];
    }
    __syncthreads();
    if (cg < 3){
      #pragma unroll
      for (int i = 0; i < 8; ++i){
        const int lin = i * 256 + tid;
        const int n = lin >> 5, ck = lin & 31;
        breg[i] = *(const s16x8*)(Bw + (size_t)((cg + 1) * 64 + n) * DK + ck * 8);
      }
    }
    f4_t acc[4];
    #pragma unroll
    for (int i = 0; i < 4; ++i) acc[i] = (f4_t){0.f, 0.f, 0.f, 0.f};
    #pragma unroll
    for (int kk = 0; kk < 8; ++kk){
      const int kb = kh * 16 + kk * 64;
      const s16x8 a = *(const s16x8*)((char*)As + (wv * 16 + r16) * 512 + (kb ^ swsel));
      #pragma unroll
      for (int nt = 0; nt < 4; ++nt){
        const s16x8 b = *(const s16x8*)((char*)Bs + (nt * 16 + r16) * 512 + (kb ^ swsel));
        acc[nt] = __builtin_amdgcn_mfma_f32_16x16x32_bf16(a, b, acc[nt], 0, 0, 0);
      }
    }
    #pragma unroll
    for (int nt = 0; nt < 4; ++nt){
      const int n = cg * 64 + nt * 16 + r16;
      const int h = n >> 5, hd = n & 31;
      const float bv = bval[n];
      #pragma unroll
      for (int rix = 0; rix < 4; ++rix){
        const int m = mbase + wv * 16 + kh * 4 + rix;   // global m = r*16384 + pix
        const int r = m >> 14, pix = m & (QN - 1);
        vbf[(size_t)((r * 8 + h) * QN + pix) * 32 + hd] = f2bf(acc[nt][rix] + bv);
      }
    }
    __syncthreads();
  }
}

// =============== K2: offsets + logits, BM=32 variant ============================
// 4 waves: wave = (mg = wv&1) rows x (ch = wv>>1) 32-col half; NT=2; 3 col-groups.
__global__ __launch_bounds__(256, 2) void k_gemm_oa(const float* __restrict__ A,
    const short* __restrict__ Bw, const float* __restrict__ boff,
    const float* __restrict__ battn, float* __restrict__ offw,
    float* __restrict__ logit){
  __shared__ short As[32 * 256];
  __shared__ short Bs[64 * 256];
  const int tid = threadIdx.x;
  const int lane = tid & 63, wv = tid >> 6;
  const int r16 = lane & 15, kh = lane >> 4;
  const int mg = wv & 1, ch = wv >> 1;
  const int swsel = (r16 & 7) << 4;
  const int mbase = blockIdx.x * 32;

  #pragma unroll
  for (int i = 0; i < 8; ++i){
    const int lin = i * 256 + tid;
    const int r = lin >> 6, ck = lin & 63;
    const f4_t v = *(const f4_t*)(A + (size_t)(mbase + r) * DK + ck * 4);
    s16x4 o = { f2bf(v[0]), f2bf(v[1]), f2bf(v[2]), f2bf(v[3]) };
    *(s16x4*)((char*)As + r * 512 + ((ck * 8) ^ ((r & 7) << 4))) = o;
  }
  s16x8 breg[8];
  #pragma unroll
  for (int i = 0; i < 8; ++i){
    const int lin = i * 256 + tid;
    const int n = lin >> 5, ck = lin & 31;
    breg[i] = *(const s16x8*)(Bw + (size_t)n * DK + ck * 8);
  }
  __syncthreads();

  for (int cg = 0; cg < 3; ++cg){
    #pragma unroll
    for (int i = 0; i < 8; ++i){
      const int lin = i * 256 + tid;
      const int n = lin >> 5, ck = lin & 31;
      *(s16x8*)((char*)Bs + n * 512 + ((ck * 16) ^ ((n & 7) << 4))) = breg[i];
    }
    __syncthreads();
    if (cg < 2){
      #pragma unroll
      for (int i = 0; i < 8; ++i){
        const int lin = i * 256 + tid;
        const int n = lin >> 5, ck = lin & 31;
        breg[i] = *(const s16x8*)(Bw + (size_t)((cg + 1) * 64 + n) * DK + ck * 8);
      }
    }
    f4_t acc[2];
    acc[0] = (f4_t){0.f,0.f,0.f,0.f}; acc[1] = (f4_t){0.f,0.f,0.f,0.f};
    #pragma unroll
    for (int kk = 0; kk < 8; ++kk){
      const int kb = kh * 16 + kk * 64;
      const s16x8 a = *(const s16x8*)((char*)As + (mg * 16 + r16) * 512 + (kb ^ swsel));
      #pragma unroll
      for (int nt = 0; nt < 2; ++nt){
        const s16x8 b = *(const s16x8*)((char*)Bs + (ch * 32 + nt * 16 + r16) * 512 + (kb ^ swsel));
        acc[nt] = __builtin_amdgcn_mfma_f32_16x16x32_bf16(a, b, acc[nt], 0, 0, 0);
      }
    }
    #pragma unroll
    for (int nt = 0; nt < 2; ++nt){
      const int n = cg * 64 + ch * 32 + nt * 16 + r16;
      #pragma unroll
      for (int rix = 0; rix < 4; ++rix){
        const int m = mbase + mg * 16 + kh * 4 + rix;
        const float v = acc[nt][rix];
        if (n < 128) offw[(size_t)m * 128 + n] = v + boff[n];
        else         logit[(size_t)m * 64 + (n - 128)] = v + battn[n - 128];
      }
    }
    __syncthreads();
  }
}

// =============== K4: output projection + bias + residual, BM=32 =================
__global__ __launch_bounds__(256, 2) void k_gemm_out(const float* __restrict__ A,
    const short* __restrict__ Bw, const float* __restrict__ bout,
    const float* __restrict__ query, float* __restrict__ out){
  __shared__ short As[32 * 256];
  __shared__ short Bs[64 * 256];
  const int tid = threadIdx.x;
  const int lane = tid & 63, wv = tid >> 6;
  const int r16 = lane & 15, kh = lane >> 4;
  const int mg = wv & 1, ch = wv >> 1;
  const int swsel = (r16 & 7) << 4;
  const int mbase = blockIdx.x * 32;

  #pragma unroll
  for (int i = 0; i < 8; ++i){
    const int lin = i * 256 + tid;
    const int r = lin >> 6, ck = lin & 63;
    const f4_t v = *(const f4_t*)(A + (size_t)(mbase + r) * DK + ck * 4);
    s16x4 o = { f2bf(v[0]), f2bf(v[1]), f2bf(v[2]), f2bf(v[3]) };
    *(s16x4*)((char*)As + r * 512 + ((ck * 8) ^ ((r & 7) << 4))) = o;
  }
  s16x8 breg[8];
  #pragma unroll
  for (int i = 0; i < 8; ++i){
    const int lin = i * 256 + tid;
    const int n = lin >> 5, ck = lin & 31;
    breg[i] = *(const s16x8*)(Bw + (size_t)n * DK + ck * 8);
  }
  __syncthreads();

  for (int cg = 0; cg < 4; ++cg){
    #pragma unroll
    for (int i = 0; i < 8; ++i){
      const int lin = i * 256 + tid;
      const int n = lin >> 5, ck = lin & 31;
      *(s16x8*)((char*)Bs + n * 512 + ((ck * 16) ^ ((n & 7) << 4))) = breg[i];
    }
    __syncthreads();
    if (cg < 3){
      #pragma unroll
      for (int i = 0; i < 8; ++i){
        const int lin = i * 256 + tid;
        const int n = lin >> 5, ck = lin & 31;
        breg[i] = *(const s16x8*)(Bw + (size_t)((cg + 1) * 64 + n) * DK + ck * 8);
      }
    }
    f4_t acc[2];
    acc[0] = (f4_t){0.f,0.f,0.f,0.f}; acc[1] = (f4_t){0.f,0.f,0.f,0.f};
    #pragma unroll
    for (int kk = 0; kk < 8; ++kk){
      const int kb = kh * 16 + kk * 64;
      const s16x8 a = *(const s16x8*)((char*)As + (mg * 16 + r16) * 512 + (kb ^ swsel));
      #pragma unroll
      for (int nt = 0; nt < 2; ++nt){
        const s16x8 b = *(const s16x8*)((char*)Bs + (ch * 32 + nt * 16 + r16) * 512 + (kb ^ swsel));
        acc[nt] = __builtin_amdgcn_mfma_f32_16x16x32_bf16(a, b, acc[nt], 0, 0, 0);
      }
    }
    #pragma unroll
    for (int nt = 0; nt < 2; ++nt){
      const int n = cg * 64 + ch * 32 + nt * 16 + r16;
      const float bo = bout[n];
      #pragma unroll
      for (int rix = 0; rix < 4; ++rix){
        const int m = mbase + mg * 16 + kh * 4 + rix;
        out[(size_t)m * DK + n] = acc[nt][rix] + bo + query[(size_t)m * DK + n];
      }
    }
    __syncthreads();
  }
}

// ---------------- K3: bilinear deformable sampling (unchanged) -------------------
__global__ __launch_bounds__(256) void k_sampler(const float* __restrict__ rp,
    const float* __restrict__ offw, const float* __restrict__ logit,
    const short* __restrict__ vbf, float* __restrict__ O2){
  const int tid = threadIdx.x;
  const int j = tid & 3;                 // hd slice: [8j, 8j+8)
  const int grp = tid >> 2;
  const int h = blockIdx.x & 7;
  const int q = (blockIdx.x >> 3) * 64 + grp;

  const float* lp = logit + (size_t)q * 64 + h * 8;
  float aw[8];
  float mx = lp[0];
  #pragma unroll
  for (int p = 1; p < 8; ++p) mx = fmaxf(mx, lp[p]);
  float s = 0.f;
  #pragma unroll
  for (int p = 0; p < 8; ++p){ float e = __expf(lp[p] - mx); aw[p] = e; s += e; }
  const float sc = 0.5f / s;
  #pragma unroll
  for (int p = 0; p < 8; ++p) aw[p] *= sc;

  const float* offp = offw + (size_t)q * 128 + h * 16;
  float acc[8] = {0.f,0.f,0.f,0.f,0.f,0.f,0.f,0.f};

  for (int r = 0; r < 2; ++r){
    const float* rpb = rp + (size_t)(r * QN + q) * 8;     // [za=4][2]
    const short* vb = vbf + (size_t)((r * 8 + h) * QN) * 32 + j * 8;
    #pragma unroll
    for (int p = 0; p < 8; ++p){
      const float x = fmaf(rpb[(p & 3) * 2 + 0], 128.f, offp[p * 2 + 0]) - 0.5f;
      const float y = fmaf(rpb[(p & 3) * 2 + 1], 128.f, offp[p * 2 + 1]) - 0.5f;
      const float xf = floorf(x), yf = floorf(y);
      const float wx = x - xf, wy = y - yf;
      const int ix = (int)xf, iy = (int)yf;
      const float vx0 = (ix >= 0 && ix < 128) ? 1.f : 0.f;
      const float vx1 = (ix + 1 >= 0 && ix + 1 < 128) ? 1.f : 0.f;
      const float vy0 = (iy >= 0 && iy < 128) ? 1.f : 0.f;
      const float vy1 = (iy + 1 >= 0 && iy + 1 < 128) ? 1.f : 0.f;
      const int ix0 = min(max(ix, 0), 127), ix1 = min(max(ix + 1, 0), 127);
      const int iy0 = min(max(iy, 0), 127), iy1 = min(max(iy + 1, 0), 127);
      const float a = aw[p];
      const float w00 = a * (1.f - wx) * (1.f - wy) * vx0 * vy0;
      const float w01 = a * wx * (1.f - wy) * vx1 * vy0;
      const float w10 = a * (1.f - wx) * wy * vx0 * vy1;
      const float w11 = a * wx * wy * vx1 * vy1;
      const s16x8 c00 = *(const s16x8*)(vb + (size_t)(iy0 * 128 + ix0) * 32);
      const s16x8 c01 = *(const s16x8*)(vb + (size_t)(iy0 * 128 + ix1) * 32);
      const s16x8 c10 = *(const s16x8*)(vb + (size_t)(iy1 * 128 + ix0) * 32);
      const s16x8 c11 = *(const s16x8*)(vb + (size_t)(iy1 * 128 + ix1) * 32);
      #pragma unroll
      for (int e = 0; e < 8; ++e){
        acc[e] = fmaf(w00, bf2f(c00[e]), acc[e]);
        acc[e] = fmaf(w01, bf2f(c01[e]), acc[e]);
        acc[e] = fmaf(w10, bf2f(c10[e]), acc[e]);
        acc[e] = fmaf(w11, bf2f(c11[e]), acc[e]);
      }
    }
  }
  float* op = O2 + (size_t)q * DK + h * 32 + j * 8;
  *(f4_t*)op       = (f4_t){acc[0], acc[1], acc[2], acc[3]};
  *(f4_t*)(op + 4) = (f4_t){acc[4], acc[5], acc[6], acc[7]};
}

extern "C" void kernel_launch(void* const* d_in, const int* in_sizes, int n_in,
                              void* d_out, int out_size, void* d_ws, size_t ws_size,
                              hipStream_t stream) {
  const float* query = (const float*)d_in[0];
  const float* value = (const float*)d_in[1];
  const float* refpt = (const float*)d_in[2];
  // d_in[3] spatial_shapes: fixed [[128,128]], hardcoded
  const float* W_off  = (const float*)d_in[4];
  const float* b_off  = (const float*)d_in[5];
  const float* W_attn = (const float*)d_in[6];
  const float* b_attn = (const float*)d_in[7];
  const float* W_val  = (const float*)d_in[8];
  const float* b_val  = (const float*)d_in[9];
  const float* W_out  = (const float*)d_in[10];
  const float* b_out  = (const float*)d_in[11];
  float* out = (float*)d_out;

  char* ws = (char*)d_ws;
  short* Wbf  = (short*)(ws);                    // 704*256 bf16          (360448 B)
  short* vbf  = (short*)(ws + 360448);           // 2*8*16384*32 bf16     (16777216 B)
  float* offw = (float*)(ws + 17137664);         // 16384*128 f32         (8388608 B)
  float* logit= (float*)(ws + 25526272);         // 16384*64 f32          (4194304 B)
  float* O2   = (float*)(ws + 29720576);         // 16384*256 f32         (16777216 B)

  k_convw   <<<dim3(704),  dim3(256), 0, stream>>>(W_val, W_off, W_attn, W_out, Wbf);
  k_gemm_val<<<dim3(512),  dim3(256), 0, stream>>>(value, Wbf, b_val, vbf);
  k_gemm_oa <<<dim3(512),  dim3(256), 0, stream>>>(query, Wbf + 256 * DK, b_off, b_attn, offw, logit);
  k_sampler <<<dim3(2048), dim3(256), 0, stream>>>(refpt, offw, logit, vbf, O2);
  k_gemm_out<<<dim3(512),  dim3(256), 0, stream>>>(O2, Wbf + 448 * DK, b_out, query, out);
}